// Round 8
// baseline (375.808 us; speedup 1.0000x reference)
//
#include <hip/hip_runtime.h>
#include <hip/hip_bf16.h>
#include <math.h>

#define NE 32        // experts
#define H 512
#define H2 1024      // 2H
#define NTOK 2048    // B*S
#define CAP 2048     // per-expert token capacity (worst case)
#define BM 64        // M-tile (tokens per block)
#define CSTR 32      // cnt cacheline-pad stride (ints): 32*4=128B per counter
#define TS1 56       // epilogue T row stride (ushorts), 112B = 16B-aligned

typedef __attribute__((ext_vector_type(8))) short bf16x8;
typedef __attribute__((ext_vector_type(4))) float f32x4;
typedef unsigned int uint;
typedef unsigned short ushort;

__device__ __forceinline__ uint bf16r(float f) {
    uint u = __float_as_uint(f);
    return (u + 0x7FFFu + ((u >> 16) & 1u)) >> 16;   // RNE
}
__device__ __forceinline__ uint pack_bf16(float a, float b) {
    return bf16r(a) | (bf16r(b) << 16);
}
__device__ __forceinline__ float bf16f(ushort u) {
    return __uint_as_float(((uint)u) << 16);
}

// ---------------------------------------------------------------------------
// Kernel 1: gating.  gate_w staged in LDS (64 KB, XOR-swizzled), coalesced.
// ---------------------------------------------------------------------------
__global__ __launch_bounds__(256) void gate_kernel(
    const float* __restrict__ x, const float* __restrict__ gate_w,
    int* __restrict__ cnt, int* __restrict__ listTok, int* __restrict__ listPair,
    float* __restrict__ listW, ushort* __restrict__ xbf)
{
    __shared__ float4 gws[4096];   // 64 KB: gate_w, piece p of row r at p^(r&7)
    const int tid = threadIdx.x;
    for (int i = tid; i < 4096; i += 256) {
        const int r = i >> 7, pp = i & 127;
        gws[(r << 7) | (pp ^ (r & 7))] = ((const float4*)gate_w)[i];
    }

    const int b = blockIdx.x;
    const int wave = tid >> 6;
    const int lane = tid & 63;
    const int t = b * 4 + wave;
    const int e = lane & 31;
    const int half = lane >> 5;

    const float4* xr = (const float4*)(x + (size_t)t * H + half * 256);
    __syncthreads();

    float acc = 0.f;
#pragma unroll 8
    for (int i = 0; i < 64; ++i) {
        const int p = half * 64 + i;
        float4 a = xr[i];
        float4 g = gws[(e << 7) | (p ^ (e & 7))];
        acc += a.x * g.x + a.y * g.y + a.z * g.z + a.w * g.w;
    }
    acc += __shfl_xor(acc, 32);

    float mx = acc;
#pragma unroll
    for (int m = 16; m >= 1; m >>= 1) mx = fmaxf(mx, __shfl_xor(mx, m));
    float p = __expf(acc - mx);
    float s = p;
#pragma unroll
    for (int m = 16; m >= 1; m >>= 1) s += __shfl_xor(s, m);
    float prob = p / s;

    int selk[4]; float wk[4]; float sum4 = 0.f;
#pragma unroll
    for (int k = 0; k < 4; ++k) {
        float v = prob; int idx = e;
#pragma unroll
        for (int m = 16; m >= 1; m >>= 1) {
            float v2 = __shfl_xor(v, m);
            int   i2 = __shfl_xor(idx, m);
            if (v2 > v || (v2 == v && i2 < idx)) { v = v2; idx = i2; }
        }
        selk[k] = idx; wk[k] = v; sum4 += v;
        if (e == idx) prob = -1.f;
    }

    if (lane < 4) {
        const int k = lane;
        const int ex = selk[k];
        const int pos = atomicAdd(&cnt[ex * CSTR], 1);
        listTok [ex * CAP + pos] = t;
        listPair[ex * CAP + pos] = t * 4 + k;
        listW   [ex * CAP + pos] = wk[k] / sum4;
    }

    const float4* xrow4 = (const float4*)(x + (size_t)t * H);
    float4 a0 = xrow4[lane * 2];
    float4 a1 = xrow4[lane * 2 + 1];
    uint4 o;
    o.x = pack_bf16(a0.x, a0.y); o.y = pack_bf16(a0.z, a0.w);
    o.z = pack_bf16(a1.x, a1.y); o.w = pack_bf16(a1.z, a1.w);
    ((uint4*)(xbf + (size_t)t * H))[lane] = o;
}

// ---------------------------------------------------------------------------
// Kernel 2: grouped GEMM1 + SiLU*up.  block = (e, 32-col chunk of 2H).
// fp32 weight panels staged ONCE into LDS (in-register convert), reused
// across all m-tiles of the expert; weights read exactly once from HBM.
// FIX vs R7: rolling single-deep A-prefetch (R6-proven pattern) — load
// it+1's fragments before the MFMA cluster of it, hiding ~200cy L2 latency.
// Panel layout: piece p (8 bf16) of row n at slot p^(n&7)  [verified].
// ---------------------------------------------------------------------------
__global__ __launch_bounds__(256, 2) void moe_gemm1(
    const float* __restrict__ wg, const float* __restrict__ wu,
    const ushort* __restrict__ xbf, const int* __restrict__ cnt,
    const int* __restrict__ listTok, const int* __restrict__ listPair,
    const float* __restrict__ listW, ushort* __restrict__ hidden)
{
    const int e  = blockIdx.x & 31;          // interleave experts for balance
    const int ch = blockIdx.x >> 5;          // 32 chunks x 32 cols = 1024 = 2H
    const int count = cnt[e * CSTR];
    if (count == 0) return;

    __shared__ ushort smem[2 * 16384 + 64 * TS1];   // G|U panels 64 KB + T 7 KB
    ushort* T = smem + 32768;

    const int tid  = threadIdx.x;
    const int lane = tid & 63;
    const int w    = tid >> 6;
    const int wm   = w & 1;      // M-half (32 rows)
    const int wn   = w >> 1;     // N-half (16 cols)
    const int l15  = lane & 15;
    const int quad = lane >> 4;

    // ---- stage both panels: 4096 pieces of 16 B, 16 per thread ----
#pragma unroll
    for (int j = 0; j < 16; ++j) {
        const int id = j * 256 + tid;
        const int p  = id & 7;
        const int s  = (id >> 3) & 7;
        const int n  = (id >> 6) & 31;
        const int pid = id >> 11;
        const float* src = (pid ? wu : wg)
            + ((size_t)e * H2 + (size_t)(ch * 32 + n)) * H + s * 64 + p * 8;
        const float4* s4 = (const float4*)src;
        float4 x0 = s4[0], x1 = s4[1];
        uint4 v;
        v.x = pack_bf16(x0.x, x0.y); v.y = pack_bf16(x0.z, x0.w);
        v.z = pack_bf16(x1.x, x1.y); v.w = pack_bf16(x1.z, x1.w);
        *(uint4*)(smem + pid * 16384 + n * 512 + s * 64 + ((p ^ (n & 7)) << 3)) = v;
    }
    __syncthreads();

    const f32x4 fz = {0.f, 0.f, 0.f, 0.f};
    const int nmt = (count + 63) >> 6;
    for (int mt = 0; mt < nmt; ++mt) {
        const int m0 = mt * BM;
        const int r0 = m0 + wm * 32 + l15;
        const int r1 = r0 + 16;
        const int atok0 = (r0 < count) ? listTok[e * CAP + r0] : 0;
        const int atok1 = (r1 < count) ? listTok[e * CAP + r1] : 0;
        const uint4* ap0 = (const uint4*)(xbf + (size_t)atok0 * H);
        const uint4* ap1 = (const uint4*)(xbf + (size_t)atok1 * H);

        f32x4 ag0 = fz, ag1 = fz, au0 = fz, au1 = fz;
        // rolling prefetch: it=0 fragments
        uint4 a00 = ap0[quad],     a01 = ap0[4 + quad];
        uint4 a10 = ap1[quad],     a11 = ap1[4 + quad];
#pragma unroll
        for (int it = 0; it < 8; ++it) {
            const int itn = (it < 7) ? it + 1 : 7;
            uint4 n00 = ap0[itn * 8 + quad], n01 = ap0[itn * 8 + 4 + quad];
            uint4 n10 = ap1[itn * 8 + quad], n11 = ap1[itn * 8 + 4 + quad];
#pragma unroll
            for (int ks = 0; ks < 2; ++ks) {
                const int n = wn * 16 + l15;
                const int idx = n * 512 + it * 64 + (((ks * 4 + quad) ^ (n & 7)) << 3);
                bf16x8 bg = *(const bf16x8*)(smem + idx);
                bf16x8 bu = *(const bf16x8*)(smem + 16384 + idx);
                bf16x8 af0 = ks ? *(bf16x8*)&a01 : *(bf16x8*)&a00;
                bf16x8 af1 = ks ? *(bf16x8*)&a11 : *(bf16x8*)&a10;
                ag0 = __builtin_amdgcn_mfma_f32_16x16x32_bf16(af0, bg, ag0, 0, 0, 0);
                ag1 = __builtin_amdgcn_mfma_f32_16x16x32_bf16(af1, bg, ag1, 0, 0, 0);
                au0 = __builtin_amdgcn_mfma_f32_16x16x32_bf16(af0, bu, au0, 0, 0, 0);
                au1 = __builtin_amdgcn_mfma_f32_16x16x32_bf16(af1, bu, au1, 0, 0, 0);
            }
            a00 = n00; a01 = n01; a10 = n10; a11 = n11;
        }

        __syncthreads();   // previous tile's T store-phase reads done
#pragma unroll
        for (int r = 0; r < 4; ++r) {
            int row = wm * 32 + quad * 4 + r;        // mb0
            int slot2 = m0 + row;
            float wgt = (slot2 < count) ? listW[e * CAP + slot2] : 0.f;
            float gv = ag0[r], uv = au0[r];
            T[row * TS1 + wn * 16 + l15] =
                (ushort)bf16r((gv / (1.f + __expf(-gv))) * uv * wgt);
            row += 16; slot2 += 16;                  // mb1
            wgt = (slot2 < count) ? listW[e * CAP + slot2] : 0.f;
            gv = ag1[r]; uv = au1[r];
            T[row * TS1 + wn * 16 + l15] =
                (ushort)bf16r((gv / (1.f + __expf(-gv))) * uv * wgt);
        }
        __syncthreads();
        {
            const int row = tid >> 2, qp = tid & 3;  // 4 thr x 16B = 64B/row
            const int slot2 = m0 + row;
            if (slot2 < count) {
                const int pr = listPair[e * CAP + slot2];
                ((uint4*)(hidden + (size_t)pr * H2 + ch * 32))[qp] =
                    ((const uint4*)(T + row * TS1))[qp];
            }
        }
    }
}

// ---------------------------------------------------------------------------
// Kernel 3: grouped GEMM2.  block = (e, ks2 K-half, 32-col chunk of H).
// Single persistent wd panel (32 KB); same rolling-prefetch fix.
// ---------------------------------------------------------------------------
__global__ __launch_bounds__(256, 2) void moe_gemm2(
    const float* __restrict__ wd, const ushort* __restrict__ hidden,
    const int* __restrict__ cnt, const int* __restrict__ listPair,
    ushort* __restrict__ pairOut)
{
    const int bid = blockIdx.x;
    const int e   = bid & 31;                // interleave experts for balance
    const int ks2 = (bid >> 5) & 1;
    const int ch  = bid >> 6;                // 16 chunks x 32 cols = 512 = H
    const int count = cnt[e * CSTR];
    if (count == 0) return;

    __shared__ ushort smem[16384 + 64 * TS1];   // panel 32 KB + T 7 KB
    ushort* T = smem + 16384;

    const int tid  = threadIdx.x;
    const int lane = tid & 63;
    const int w    = tid >> 6;
    const int wm   = w & 1;
    const int wn   = w >> 1;
    const int l15  = lane & 15;
    const int quad = lane >> 4;

    // ---- stage panel: 2048 pieces, 8 per thread ----
#pragma unroll
    for (int j = 0; j < 8; ++j) {
        const int id = j * 256 + tid;
        const int p  = id & 7;
        const int s  = (id >> 3) & 7;
        const int n  = (id >> 6) & 31;
        const float* src = wd
            + ((size_t)e * H + (size_t)(ch * 32 + n)) * H2 + ks2 * 512 + s * 64 + p * 8;
        const float4* s4 = (const float4*)src;
        float4 x0 = s4[0], x1 = s4[1];
        uint4 v;
        v.x = pack_bf16(x0.x, x0.y); v.y = pack_bf16(x0.z, x0.w);
        v.z = pack_bf16(x1.x, x1.y); v.w = pack_bf16(x1.z, x1.w);
        *(uint4*)(smem + n * 512 + s * 64 + ((p ^ (n & 7)) << 3)) = v;
    }
    __syncthreads();

    const f32x4 fz = {0.f, 0.f, 0.f, 0.f};
    const int nmt = (count + 63) >> 6;
    for (int mt = 0; mt < nmt; ++mt) {
        const int m0 = mt * BM;
        const int r0 = m0 + wm * 32 + l15;
        const int r1 = r0 + 16;
        const int apr0 = (r0 < count) ? listPair[e * CAP + r0] : 0;
        const int apr1 = (r1 < count) ? listPair[e * CAP + r1] : 0;
        const uint4* ap0 = (const uint4*)(hidden + (size_t)apr0 * H2 + ks2 * 512);
        const uint4* ap1 = (const uint4*)(hidden + (size_t)apr1 * H2 + ks2 * 512);

        f32x4 c0 = fz, c1 = fz;
        uint4 a00 = ap0[quad],     a01 = ap0[4 + quad];
        uint4 a10 = ap1[quad],     a11 = ap1[4 + quad];
#pragma unroll
        for (int it = 0; it < 8; ++it) {
            const int itn = (it < 7) ? it + 1 : 7;
            uint4 n00 = ap0[itn * 8 + quad], n01 = ap0[itn * 8 + 4 + quad];
            uint4 n10 = ap1[itn * 8 + quad], n11 = ap1[itn * 8 + 4 + quad];
#pragma unroll
            for (int ks = 0; ks < 2; ++ks) {
                const int n = wn * 16 + l15;
                const int idx = n * 512 + it * 64 + (((ks * 4 + quad) ^ (n & 7)) << 3);
                bf16x8 bb = *(const bf16x8*)(smem + idx);
                bf16x8 af0 = ks ? *(bf16x8*)&a01 : *(bf16x8*)&a00;
                bf16x8 af1 = ks ? *(bf16x8*)&a11 : *(bf16x8*)&a10;
                c0 = __builtin_amdgcn_mfma_f32_16x16x32_bf16(af0, bb, c0, 0, 0, 0);
                c1 = __builtin_amdgcn_mfma_f32_16x16x32_bf16(af1, bb, c1, 0, 0, 0);
            }
            a00 = n00; a01 = n01; a10 = n10; a11 = n11;
        }

        __syncthreads();
#pragma unroll
        for (int r = 0; r < 4; ++r) {
            int row = wm * 32 + quad * 4 + r;
            T[row * TS1 + wn * 16 + l15] = (ushort)bf16r(c0[r]);
            T[(row + 16) * TS1 + wn * 16 + l15] = (ushort)bf16r(c1[r]);
        }
        __syncthreads();
        {
            const int row = tid >> 2, qp = tid & 3;
            const int slot2 = m0 + row;
            if (slot2 < count) {
                const int pr = listPair[e * CAP + slot2];
                ((uint4*)(pairOut + ((size_t)(ks2 << 13) + pr) * H + ch * 32))[qp] =
                    ((const uint4*)(T + row * TS1))[qp];
            }
        }
    }
}

// ---------------------------------------------------------------------------
// Kernel 4: combine — out[t][c] = sum over k(4) x split(2). Overwrites d_out.
// ---------------------------------------------------------------------------
__global__ __launch_bounds__(256) void combine_kernel(
    const ushort* __restrict__ pairOut, float* __restrict__ out)
{
    const int tok = blockIdx.x * 4 + (threadIdx.x >> 6);
    const int c   = (threadIdx.x & 63) * 8;
    float s[8];
#pragma unroll
    for (int i = 0; i < 8; ++i) s[i] = 0.f;
#pragma unroll
    for (int j = 0; j < 8; ++j) {
        const int row = ((j >> 2) << 13) + tok * 4 + (j & 3);
        uint4 v = *(const uint4*)(pairOut + (size_t)row * H + c);
        const ushort* u = (const ushort*)&v;
#pragma unroll
        for (int i = 0; i < 8; ++i) s[i] += bf16f(u[i]);
    }
    float4* o = (float4*)(out + (size_t)tok * H + c);
    o[0] = make_float4(s[0], s[1], s[2], s[3]);
    o[1] = make_float4(s[4], s[5], s[6], s[7]);
}

// ---------------------------------------------------------------------------
extern "C" void kernel_launch(void* const* d_in, const int* in_sizes, int n_in,
                              void* d_out, int out_size, void* d_ws, size_t ws_size,
                              hipStream_t stream)
{
    (void)in_sizes; (void)n_in; (void)out_size; (void)ws_size;
    const float* x      = (const float*)d_in[0];
    const float* gate_w = (const float*)d_in[1];
    const float* w_gate = (const float*)d_in[2];
    const float* w_up   = (const float*)d_in[3];
    const float* w_down = (const float*)d_in[4];

    char* ws = (char*)d_ws;
    int* cnt = (int*)ws;                    // NE*CSTR*4 = 4096 B (padded lines)

    size_t off = 8192;
    int*    listTok  = (int*)(ws + off);   off += (size_t)NE * CAP * 4;
    int*    listPair = (int*)(ws + off);   off += (size_t)NE * CAP * 4;
    float*  listW    = (float*)(ws + off); off += (size_t)NE * CAP * 4;
    ushort* xbf      = (ushort*)(ws + off); off += (size_t)NTOK * H * 2;
    ushort* hidden   = (ushort*)(ws + off); off += (size_t)NTOK * 4 * H2 * 2;    // 16 MB
    ushort* pairOut  = (ushort*)(ws + off); off += (size_t)2 * NTOK * 4 * H * 2; // 16 MB

    hipMemsetAsync(ws, 0, 4352, stream);

    gate_kernel<<<512, 256, 0, stream>>>(
        x, gate_w, cnt, listTok, listPair, listW, xbf);
    moe_gemm1<<<NE * 32, 256, 0, stream>>>(
        w_gate, w_up, xbf, cnt, listTok, listPair, listW, hidden);
    moe_gemm2<<<NE * 32, 256, 0, stream>>>(
        w_down, hidden, cnt, listPair, pairOut);
    combine_kernel<<<NTOK / 4, 256, 0, stream>>>(pairOut, (float*)d_out);
}

// Round 9
// 280.886 us; speedup vs baseline: 1.3379x; 1.3379x over previous
//
#include <hip/hip_runtime.h>
#include <hip/hip_bf16.h>
#include <math.h>

#define NE 32        // experts
#define H 512
#define H2 1024      // 2H
#define NTOK 2048    // B*S
#define CAP 2048     // per-expert token capacity (worst case)
#define BM 64        // M-tile (tokens per block)
#define MAXT64 160   // sum_e ceil(cnt_e/64) <= 32 + 8192/64 = 160
#define TSTRIDE 144  // epilogue transpose row stride (ushorts)
#define CSTR 32      // cnt cacheline-pad stride (ints): 32*4=128B per counter
#define CVTB 2048    // wg+wu convert blocks fused into prep launch
#define WDTB 512     // wd-convert blocks mapped FIRST in gemm1's launch

typedef __attribute__((ext_vector_type(8))) short bf16x8;
typedef __attribute__((ext_vector_type(4))) float f32x4;
typedef unsigned int uint;
typedef unsigned short ushort;

__device__ __forceinline__ uint bf16r(float f) {
    uint u = __float_as_uint(f);
    return (u + 0x7FFFu + ((u >> 16) & 1u)) >> 16;   // RNE
}
__device__ __forceinline__ uint pack_bf16(float a, float b) {
    return bf16r(a) | (bf16r(b) << 16);
}
__device__ __forceinline__ float bf16f(ushort u) {
    return __uint_as_float(((uint)u) << 16);
}

// async 16-B global->LDS DMA; LDS dest is wave-uniform base + lane*16
__device__ __forceinline__ void dma16(const void* g, void* l) {
    __builtin_amdgcn_global_load_lds(
        (const __attribute__((address_space(1))) uint*)g,
        (__attribute__((address_space(3))) uint*)l, 16, 0, 0);
}

// grid-stride fp32 -> bf16 convert of one matrix (nch 8-float chunks).
__device__ __forceinline__ void cvt_mat(const float* __restrict__ src,
                                        ushort* __restrict__ dst,
                                        int tg, int nt, int nch)
{
    for (int c = tg; c < nch; c += nt) {
        const f32x4* s = (const f32x4*)src + (size_t)c * 2;
        f32x4 x0 = __builtin_nontemporal_load(s);
        f32x4 x1 = __builtin_nontemporal_load(s + 1);
        uint4 v;
        v.x = pack_bf16(x0.x, x0.y); v.y = pack_bf16(x0.z, x0.w);
        v.z = pack_bf16(x1.x, x1.y); v.w = pack_bf16(x1.z, x1.w);
        ((uint4*)dst)[c] = v;
    }
}

// ---------------------------------------------------------------------------
// Kernel 1: prep = gating (blocks 0..511, zero-LDS R4-verified form) +
// wg/wu fp32->bf16 convert (blocks 512.., grid-stride) — fused so the
// converts overlap the gating blocks instead of running serially after.
// ---------------------------------------------------------------------------
__global__ __launch_bounds__(256) void prep_kernel(
    const float* __restrict__ x, const float* __restrict__ gate_w,
    int* __restrict__ cnt, int* __restrict__ listTok, int* __restrict__ listPair,
    float* __restrict__ listW, ushort* __restrict__ xbf,
    const float* __restrict__ wg, const float* __restrict__ wu,
    ushort* __restrict__ wgb, ushort* __restrict__ wub)
{
    const int b = blockIdx.x;
    if (b >= 512) {
        const int tg = (b - 512) * 256 + (int)threadIdx.x;
        const int nt = CVTB * 256;
        const int nch = NE * H2 * H / 8;   // 2097152 chunks per matrix
        cvt_mat(wg, wgb, tg, nt, nch);
        cvt_mat(wu, wub, tg, nt, nch);
        return;
    }

    const int wave = threadIdx.x >> 6;
    const int lane = threadIdx.x & 63;
    const int t = b * 4 + wave;
    const int e = lane & 31;
    const int half = lane >> 5;

    const float4* xr = (const float4*)(x + (size_t)t * H + half * 256);
    const float4* gr = (const float4*)(gate_w + (size_t)e * H + half * 256);
    float acc = 0.f;
#pragma unroll 8
    for (int i = 0; i < 64; ++i) {
        float4 a = xr[i], g = gr[i];
        acc += a.x * g.x + a.y * g.y + a.z * g.z + a.w * g.w;
    }
    acc += __shfl_xor(acc, 32);

    float mx = acc;
#pragma unroll
    for (int m = 16; m >= 1; m >>= 1) mx = fmaxf(mx, __shfl_xor(mx, m));
    float p = __expf(acc - mx);
    float s = p;
#pragma unroll
    for (int m = 16; m >= 1; m >>= 1) s += __shfl_xor(s, m);
    float prob = p / s;

    int selk[4]; float wk[4]; float sum4 = 0.f;
#pragma unroll
    for (int k = 0; k < 4; ++k) {
        float v = prob; int idx = e;
#pragma unroll
        for (int m = 16; m >= 1; m >>= 1) {
            float v2 = __shfl_xor(v, m);
            int   i2 = __shfl_xor(idx, m);
            if (v2 > v || (v2 == v && i2 < idx)) { v = v2; idx = i2; }
        }
        selk[k] = idx; wk[k] = v; sum4 += v;
        if (e == idx) prob = -1.f;
    }

    // 4 parallel atomics (lanes 0..3), each to its own padded cacheline
    if (lane < 4) {
        const int k = lane;
        const int ex = selk[k];
        const int pos = atomicAdd(&cnt[ex * CSTR], 1);
        listTok [ex * CAP + pos] = t;
        listPair[ex * CAP + pos] = t * 4 + k;
        listW   [ex * CAP + pos] = wk[k] / sum4;
    }

    const float4* xrow4 = (const float4*)(x + (size_t)t * H);
    float4 a0 = xrow4[lane * 2];
    float4 a1 = xrow4[lane * 2 + 1];
    uint4 o;
    o.x = pack_bf16(a0.x, a0.y); o.y = pack_bf16(a0.z, a0.w);
    o.z = pack_bf16(a1.x, a1.y); o.w = pack_bf16(a1.z, a1.w);
    ((uint4*)(xbf + (size_t)t * H))[lane] = o;
}

// ---------------------------------------------------------------------------
// Kernel 1b: scheduler — dense (expert, mtile64) worklist. 1 wave.
// ---------------------------------------------------------------------------
__global__ void sched_kernel(const int* __restrict__ cnt,
                             int* __restrict__ ntiles, int* __restrict__ desc)
{
    const int lane = threadIdx.x;
    int t = 0;
    if (lane < NE) t = (cnt[lane * CSTR] + 63) >> 6;
    int pre = t;
#pragma unroll
    for (int m = 1; m < 64; m <<= 1) {
        int v = __shfl_up(pre, m);
        if (lane >= m) pre += v;
    }
    const int off = pre - t;
    if (lane < NE)
        for (int i = 0; i < t; ++i) desc[off + i] = (lane << 16) | i;
    if (lane == 63) *ntiles = pre;
}

// ---------------------------------------------------------------------------
// Kernel 2: grouped GEMM1 + SiLU*up, scaled by combine weight.
// WB path: wd-convert blocks are mapped FIRST (item < WDTB) so they are
// dispatched alongside the GEMM blocks and overlap, instead of running as
// a serialized ~25us tail.  Launch boundary orders wdb before gemm2.
// ---------------------------------------------------------------------------
template<bool WB>
__global__ __launch_bounds__(256, 4) void moe_gemm1(
    const void* __restrict__ wgate_, const void* __restrict__ wup_,
    const ushort* __restrict__ xbf, const int* __restrict__ cnt,
    const int* __restrict__ listTok, const int* __restrict__ listPair,
    const float* __restrict__ listW, ushort* __restrict__ hidden,
    const int* __restrict__ ntiles, const int* __restrict__ desc,
    const float* __restrict__ wdF, ushort* __restrict__ wdb_)
{
    int item = blockIdx.x;
    if (WB) {
        if (item < WDTB) {
            const int tg = item * 256 + (int)threadIdx.x;
            cvt_mat(wdF, wdb_, tg, WDTB * 256, NE * H * H2 / 8);
            return;
        }
        item -= WDTB;
    }
    if (item >= (*ntiles) * 8) return;
    const int d  = desc[item >> 3];
    const int ch = item & 7;
    const int e  = d >> 16;
    const int mt = d & 0xffff;
    const int count = cnt[e * CSTR];
    const int m0 = mt * BM;

    __shared__ ushort smem[2 * 128 * 64];   // 32 KB: Gs | Us; epilogue T overlays
    ushort* Gs = smem;
    ushort* Us = smem + 128 * 64;

    const int tid  = threadIdx.x;
    const int lane = tid & 63;
    const int w    = tid >> 6;
    const int l15  = lane & 15;
    const int quad = lane >> 4;

    // A row (token) for this lane
    const int arow = m0 + w * 16 + l15;
    const int atok = (arow < count) ? listTok[e * CAP + arow] : 0;
    const char* aptr = (const char*)(xbf + (size_t)atok * H);

    // bf16 DMA staging coords: lane -> (row w*32 + i*8 + rr, piece p^rr)
    const int rr = lane >> 3;   // 0..7
    const int p  = lane & 7;
    const char* gsrc = nullptr; const char* usrc = nullptr;
    // fp32 fallback staging coords
    const int sr = tid >> 1;    // 0..127
    const int sh = tid & 1;
    const float* gF = nullptr; const float* uF = nullptr;
    if (WB) {
        const ushort* wgp = (const ushort*)wgate_;
        const ushort* wup = (const ushort*)wup_;
        const size_t rowi = (size_t)e * H2 + (size_t)(ch * 128 + w * 32 + rr);
        gsrc = (const char*)(wgp + rowi * H) + ((p ^ rr) << 4);
        usrc = (const char*)(wup + rowi * H) + ((p ^ rr) << 4);
    } else {
        gF = (const float*)wgate_ + ((size_t)e * H2 + (size_t)(ch * 128 + sr)) * H;
        uF = (const float*)wup_   + ((size_t)e * H2 + (size_t)(ch * 128 + sr)) * H;
    }

    f32x4 accg[8], accu[8];
    const f32x4 fz = {0.f, 0.f, 0.f, 0.f};
#pragma unroll
    for (int ni = 0; ni < 8; ++ni) { accg[ni] = fz; accu[ni] = fz; }

    // A prefetch for iter 0
    uint4 a0 = *(const uint4*)(aptr + quad * 16);
    uint4 a1 = *(const uint4*)(aptr + 64 + quad * 16);

    for (int it = 0; it < 8; ++it) {
        __syncthreads();   // prior iter's LDS reads done before overwrite
        if (WB) {
#pragma unroll
            for (int i = 0; i < 4; ++i) {
                dma16(gsrc + i * (8 * H * 2), (char*)Gs + w * 4096 + i * 1024);
                dma16(usrc + i * (8 * H * 2), (char*)Us + w * 4096 + i * 1024);
            }
        } else {
#pragma unroll
            for (int i = 0; i < 4; ++i) {
                const int pslot = sh * 4 + i;
                const int pc = pslot ^ (sr & 7);
                const float4* s1 = (const float4*)(gF + it * 64 + pc * 8);
                float4 g0 = s1[0], g1 = s1[1];
                uint4 v;
                v.x = pack_bf16(g0.x, g0.y); v.y = pack_bf16(g0.z, g0.w);
                v.z = pack_bf16(g1.x, g1.y); v.w = pack_bf16(g1.z, g1.w);
                ((uint4*)Gs)[sr * 8 + pslot] = v;
                const float4* s2 = (const float4*)(uF + it * 64 + pc * 8);
                float4 u0 = s2[0], u1 = s2[1];
                uint4 q;
                q.x = pack_bf16(u0.x, u0.y); q.y = pack_bf16(u0.z, u0.w);
                q.z = pack_bf16(u1.x, u1.y); q.w = pack_bf16(u1.z, u1.w);
                ((uint4*)Us)[sr * 8 + pslot] = q;
            }
        }
        // A prefetch next iter
        const int itn = (it < 7) ? it + 1 : 7;
        uint4 an0 = *(const uint4*)(aptr + itn * 128 + quad * 16);
        uint4 an1 = *(const uint4*)(aptr + itn * 128 + 64 + quad * 16);
        __syncthreads();   // drains DMA (vmcnt0) + LDS writes visible

#pragma unroll
        for (int ks = 0; ks < 2; ++ks) {
            bf16x8 af = ks ? *(bf16x8*)&a1 : *(bf16x8*)&a0;
#pragma unroll
            for (int ni = 0; ni < 8; ++ni) {
                const int n = ni * 16 + l15;
                const int slot = n * 8 + ((ks * 4 + quad) ^ (n & 7));
                bf16x8 bg = ((const bf16x8*)Gs)[slot];
                bf16x8 bu = ((const bf16x8*)Us)[slot];
                accg[ni] = __builtin_amdgcn_mfma_f32_16x16x32_bf16(af, bg, accg[ni], 0, 0, 0);
                accu[ni] = __builtin_amdgcn_mfma_f32_16x16x32_bf16(af, bu, accu[ni], 0, 0, 0);
            }
        }
        a0 = an0; a1 = an1;
        if (WB) { gsrc += 128; usrc += 128; }
    }

    // epilogue: hidden = silu(g)*u * w_pair -> LDS transpose -> coalesced store
    __syncthreads();
    ushort* T = smem;
#pragma unroll
    for (int r = 0; r < 4; ++r) {
        const int row = w * 16 + quad * 4 + r;
        const int slot2 = m0 + row;
        const float wgt = (slot2 < count) ? listW[e * CAP + slot2] : 0.f;
#pragma unroll
        for (int ni = 0; ni < 8; ++ni) {
            float gv = accg[ni][r], uv = accu[ni][r];
            float hv = (gv / (1.f + __expf(-gv))) * uv * wgt;
            T[row * TSTRIDE + ni * 16 + l15] = (ushort)bf16r(hv);
        }
    }
    __syncthreads();
    {
        const int row = tid >> 2;      // 0..63
        const int qp  = tid & 3;       // 4 threads/row x 4 uint4 = 256 B/row
        const int slot2 = m0 + row;
        if (slot2 < count) {
            const int pr = listPair[e * CAP + slot2];
            uint4* dst = (uint4*)(hidden + (size_t)pr * H2 + ch * 128) + qp * 4;
            const uint4* src = (const uint4*)(T + row * TSTRIDE) + qp * 4;
#pragma unroll
            for (int i = 0; i < 4; ++i) dst[i] = src[i];
        }
    }
}

// ---------------------------------------------------------------------------
// Kernel 3: grouped GEMM2: pairOut[ks2][pair][H-chunk] = hidden @ wd^T
// item = tile*8 + ks2*4 + ch.
// ---------------------------------------------------------------------------
template<bool WB>
__global__ __launch_bounds__(256, 4) void moe_gemm2(
    const void* __restrict__ wdown_, const ushort* __restrict__ hidden,
    const int* __restrict__ cnt, const int* __restrict__ listPair,
    ushort* __restrict__ pairOut,
    const int* __restrict__ ntiles, const int* __restrict__ desc)
{
    const int item = blockIdx.x;
    if (item >= (*ntiles) * 8) return;
    const int d   = desc[item >> 3];
    const int ks2 = (item >> 2) & 1;
    const int ch  = item & 3;
    const int e   = d >> 16;
    const int mt  = d & 0xffff;
    const int count = cnt[e * CSTR];
    const int m0 = mt * BM;

    __shared__ ushort smem[9216];   // 18 KB: Bs (16 KB); epilogue T overlays
    ushort* Bs = smem;

    const int tid  = threadIdx.x;
    const int lane = tid & 63;
    const int w    = tid >> 6;
    const int l15  = lane & 15;
    const int quad = lane >> 4;

    const int arow = m0 + w * 16 + l15;
    const int apr  = (arow < count) ? listPair[e * CAP + arow] : 0;
    const char* aptr = (const char*)(hidden + (size_t)apr * H2 + ks2 * 512);

    const int rr = lane >> 3;
    const int p  = lane & 7;
    const char* bsrc = nullptr;
    const int sr = tid >> 1;
    const int sh = tid & 1;
    const float* bF = nullptr;
    if (WB) {
        const ushort* wdp = (const ushort*)wdown_;
        const size_t rowi = (size_t)e * H + (size_t)(ch * 128 + w * 32 + rr);
        bsrc = (const char*)(wdp + rowi * H2 + ks2 * 512) + ((p ^ rr) << 4);
    } else {
        bF = (const float*)wdown_ + ((size_t)e * H + (size_t)(ch * 128 + sr)) * H2 + ks2 * 512;
    }

    f32x4 acc[8];
    const f32x4 fz = {0.f, 0.f, 0.f, 0.f};
#pragma unroll
    for (int ni = 0; ni < 8; ++ni) acc[ni] = fz;

    uint4 a0 = *(const uint4*)(aptr + quad * 16);
    uint4 a1 = *(const uint4*)(aptr + 64 + quad * 16);

    for (int it = 0; it < 8; ++it) {
        __syncthreads();
        if (WB) {
#pragma unroll
            for (int i = 0; i < 4; ++i)
                dma16(bsrc + i * (8 * H2 * 2), (char*)Bs + w * 4096 + i * 1024);
        } else {
#pragma unroll
            for (int i = 0; i < 4; ++i) {
                const int pslot = sh * 4 + i;
                const int pc = pslot ^ (sr & 7);
                const float4* s1 = (const float4*)(bF + it * 64 + pc * 8);
                float4 b0 = s1[0], b1 = s1[1];
                uint4 v;
                v.x = pack_bf16(b0.x, b0.y); v.y = pack_bf16(b0.z, b0.w);
                v.z = pack_bf16(b1.x, b1.y); v.w = pack_bf16(b1.z, b1.w);
                ((uint4*)Bs)[sr * 8 + pslot] = v;
            }
        }
        const int itn = (it < 7) ? it + 1 : 7;
        uint4 an0 = *(const uint4*)(aptr + itn * 128 + quad * 16);
        uint4 an1 = *(const uint4*)(aptr + itn * 128 + 64 + quad * 16);
        __syncthreads();

#pragma unroll
        for (int ks = 0; ks < 2; ++ks) {
            bf16x8 af = ks ? *(bf16x8*)&a1 : *(bf16x8*)&a0;
#pragma unroll
            for (int ni = 0; ni < 8; ++ni) {
                const int n = ni * 16 + l15;
                const int slot = n * 8 + ((ks * 4 + quad) ^ (n & 7));
                bf16x8 bb = ((const bf16x8*)Bs)[slot];
                acc[ni] = __builtin_amdgcn_mfma_f32_16x16x32_bf16(af, bb, acc[ni], 0, 0, 0);
            }
        }
        a0 = an0; a1 = an1;
        if (WB) bsrc += 128;
    }

    // epilogue: transpose -> coalesced bf16 partial store
    __syncthreads();
    ushort* T = smem;
#pragma unroll
    for (int r = 0; r < 4; ++r) {
        const int row = w * 16 + quad * 4 + r;
#pragma unroll
        for (int ni = 0; ni < 8; ++ni)
            T[row * TSTRIDE + ni * 16 + l15] = (ushort)bf16r(acc[ni][r]);
    }
    __syncthreads();
    {
        const int row = tid >> 2;      // 0..63
        const int qp  = tid & 3;       // 4 threads/row x 4 uint4 = 256 B/row
        const int slot2 = m0 + row;
        if (slot2 < count) {
            const int pr = listPair[e * CAP + slot2];
            uint4* dst = (uint4*)(pairOut + ((size_t)(ks2 << 13) + pr) * H + ch * 128) + qp * 4;
            const uint4* src = (const uint4*)(T + row * TSTRIDE) + qp * 4;
#pragma unroll
            for (int i = 0; i < 4; ++i) dst[i] = src[i];
        }
    }
}

// ---------------------------------------------------------------------------
// Kernel 4: combine — out[t][c] = sum over k(4) x split(2). Overwrites d_out.
// ---------------------------------------------------------------------------
__global__ __launch_bounds__(256) void combine_kernel(
    const ushort* __restrict__ pairOut, float* __restrict__ out)
{
    const int tok = blockIdx.x * 4 + (threadIdx.x >> 6);
    const int c   = (threadIdx.x & 63) * 8;
    float s[8];
#pragma unroll
    for (int i = 0; i < 8; ++i) s[i] = 0.f;
#pragma unroll
    for (int j = 0; j < 8; ++j) {
        const int row = ((j >> 2) << 13) + tok * 4 + (j & 3);
        uint4 v = *(const uint4*)(pairOut + (size_t)row * H + c);
        const ushort* u = (const ushort*)&v;
#pragma unroll
        for (int i = 0; i < 8; ++i) s[i] += bf16f(u[i]);
    }
    float4* o = (float4*)(out + (size_t)tok * H + c);
    o[0] = make_float4(s[0], s[1], s[2], s[3]);
    o[1] = make_float4(s[4], s[5], s[6], s[7]);
}

// ---------------------------------------------------------------------------
extern "C" void kernel_launch(void* const* d_in, const int* in_sizes, int n_in,
                              void* d_out, int out_size, void* d_ws, size_t ws_size,
                              hipStream_t stream)
{
    (void)in_sizes; (void)n_in; (void)out_size;
    const float* x      = (const float*)d_in[0];
    const float* gate_w = (const float*)d_in[1];
    const float* w_gate = (const float*)d_in[2];
    const float* w_up   = (const float*)d_in[3];
    const float* w_down = (const float*)d_in[4];

    char* ws = (char*)d_ws;
    int* cnt    = (int*)ws;                 // NE*CSTR*4 = 4096 B (padded lines)
    int* ntiles = (int*)(ws + 4096);
    int* desc   = (int*)(ws + 4224);        // MAXT64*4 = 640 B

    size_t off = 8192;
    int*    listTok  = (int*)(ws + off);   off += (size_t)NE * CAP * 4;
    int*    listPair = (int*)(ws + off);   off += (size_t)NE * CAP * 4;
    float*  listW    = (float*)(ws + off); off += (size_t)NE * CAP * 4;
    ushort* xbf      = (ushort*)(ws + off); off += (size_t)NTOK * H * 2;
    ushort* hidden   = (ushort*)(ws + off); off += (size_t)NTOK * 4 * H2 * 2;    // 16 MB
    ushort* pairOut  = (ushort*)(ws + off); off += (size_t)2 * NTOK * 4 * H * 2; // 16 MB
    ushort* wgb = (ushort*)(ws + off); off += (size_t)NE * H2 * H * 2;  // 32 MB
    ushort* wub = (ushort*)(ws + off); off += (size_t)NE * H2 * H * 2;  // 32 MB
    ushort* wdb = (ushort*)(ws + off); off += (size_t)NE * H * H2 * 2;  // 32 MB
    const size_t need_full = off;

    const bool full = (ws_size >= need_full);

    hipMemsetAsync(ws, 0, 4352, stream);

    if (full) {
        prep_kernel<<<512 + CVTB, 256, 0, stream>>>(
            x, gate_w, cnt, listTok, listPair, listW, xbf,
            w_gate, w_up, wgb, wub);
        sched_kernel<<<1, 64, 0, stream>>>(cnt, ntiles, desc);
        moe_gemm1<true><<<WDTB + MAXT64 * 8, 256, 0, stream>>>(
            (const void*)wgb, (const void*)wub, xbf, cnt, listTok, listPair,
            listW, hidden, ntiles, desc, w_down, wdb);
        moe_gemm2<true><<<MAXT64 * 8, 256, 0, stream>>>(
            (const void*)wdb, hidden, cnt, listPair, pairOut, ntiles, desc);
    } else {
        prep_kernel<<<512, 256, 0, stream>>>(
            x, gate_w, cnt, listTok, listPair, listW, xbf,
            nullptr, nullptr, nullptr, nullptr);
        sched_kernel<<<1, 64, 0, stream>>>(cnt, ntiles, desc);
        moe_gemm1<false><<<MAXT64 * 8, 256, 0, stream>>>(
            (const void*)w_gate, (const void*)w_up, xbf, cnt, listTok, listPair,
            listW, hidden, ntiles, desc, nullptr, nullptr);
        moe_gemm2<false><<<MAXT64 * 8, 256, 0, stream>>>(
            (const void*)w_down, hidden, cnt, listPair, pairOut, ntiles, desc);
    }
    combine_kernel<<<NTOK / 4, 256, 0, stream>>>(pairOut, (float*)d_out);
}